// Round 9
// baseline (20688.376 us; speedup 1.0000x reference)
//
#include <hip/hip_runtime.h>
#include <stdint.h>

// LSTM encoder: B=64, S=512, V=32000, E=512, H=1024. Returns final (h, c) fp32.
//
// Round-18: ROW-PARTITIONED XCD-LOCAL RECURRENCE.
// Insight: the recurrence is independent PER BATCH ROW; only the GEMM
// couples rows. r15 proved the 4.9us/step floor is producer-store-to-MALL
// visibility (~3.5-4us incl. congestion), not detection. So eliminate the
// MALL from the loop: group g = blk&7 (round-robin => one XCD) owns rows
// [8g,8g+8); its 32 same-XCD blocks split the 4096 gate-cols (128 each).
// Per-step h exchange is intra-XCD: normal stores (own-L2, ~100cyc
// visible) + sc0 sweeps (L1-bypass, L2-served ~0.2us). XCDs fully
// decoupled -- no global straggler coupling.
//  - W per block 384KB: 128KB dynamic LDS (m201-proven size) + 256
//    VGPRs/lane of B-frags. M=16 MFMA tiles, rows 8..15 padded (odd-zero,
//    init-written, never touched).
//  - Sync protocol: r13-proven virgin-slot LSB-odd validation transplanted
//    into L2: per-t mailbox slot, init-cleared even; sc0 sweep;
//    detect==fetch. No tags, no ring reuse, no stale-valid ambiguity.
//    Same-XCD normal stores update resident L2 lines in place (no
//    poisoning). Partial-store visibility caught per-u64 LSB check.
//  - Producers DUAL-STORE each unit: normal (fast path) + agent-scope to
//    the SAME address with identical bytes (benign overlap). After 24
//    bounded sc0 retry rounds consumers switch to agent loads (MALL has
//    the agent-stored copy) -> terminating under ANY block->XCD mapping;
//    adaptive kill-switch skips sc0 retries after 4 failed steps.
//  - emb GEMM (K=512, non-recurrent operands) stays in-loop as shadow
//    work from init-precomputed per-group A-fragments.

#define Bsz 64
#define Ssz 512
#define Esz 512
#define Hsz 1024
#define G4  4096
#define NBLK 256
#define GRPS 8
#define MBU 2048              // 16B units per (t, group) h mailbox slot
#define EBU 1024              // 16B units per (group, t) emb block
#define WFRAG 96              // B-frags per (GB, wave): 2 tiles x 48 kc
#define LDSF 16               // LDS-resident frags per tile per wave

typedef float f32x4 __attribute__((ext_vector_type(4)));
typedef short bf16x8 __attribute__((ext_vector_type(8)));
typedef unsigned long long u64;

// Mailbox unit(rowp<16, kc<32, q<4) = kc*64 + q*16 + rowp ; 16B = 8 bf16
//   (row rowp, k = kc*32 + q*8 + j). rows 0..7 real (global g*8+rowp),
//   rows 8..15 pad (odd-zero, init-written).
// Wf frag layout: [(GB*4+w)*96 + tile*48 + kc][lane] ; lane: col r=l&15,
//   k-octet q8=l>>4. gcol(tile,r) = (tile*2 + (r>>3))*1024 + GB*32 + w*8 + (r&7)

__device__ __forceinline__ unsigned short f2bf(float f) {
  union { float f; uint32_t u; } v; v.f = f;
  return (unsigned short)((v.u + 0x7FFFu + ((v.u >> 16) & 1u)) >> 16);  // RNE
}
__device__ __forceinline__ unsigned short f2bf_odd(float f) {
  union { float f; uint32_t u; } v; v.f = f;
  return (unsigned short)((v.u >> 16) | 1u);   // nearest odd-LSB (validity)
}
__device__ __forceinline__ float fsig(float x) {
  return __builtin_amdgcn_rcpf(1.0f + __expf(-x));
}
__device__ __forceinline__ float ftanh(float x) {
  return 2.0f * fsig(2.0f * x) - 1.0f;
}

__global__ __launch_bounds__(256) void wf_kernel(
    const float* __restrict__ Wih, const float* __restrict__ Whh,
    unsigned short* __restrict__ Wf)
{
  const int gid  = blockIdx.x * 256 + threadIdx.x;
  const int lane = gid & 63;
  const int fg   = gid >> 6;                 // [0, 12288)
  const int kc   = fg % 48;
  const int tile = (fg / 48) & 1;
  const int w    = (fg / 96) & 3;
  const int GB   = fg / 384;
  const int r = lane & 15, q8 = lane >> 4;
  const int gcol = (tile * 2 + (r >> 3)) * 1024 + GB * 32 + w * 8 + (r & 7);
  const int k0 = kc * 32 + q8 * 8;
  unsigned short pack[8];
  #pragma unroll
  for (int j = 0; j < 8; ++j) {
    const int k = k0 + j;
    const float v = (k < Hsz) ? Whh[(size_t)k * G4 + gcol]
                              : Wih[(size_t)(k - Hsz) * G4 + gcol];
    pack[j] = f2bf(v);
  }
  *(bf16x8*)(Wf + ((size_t)fg * 64 + lane) * 8) = *(bf16x8*)pack;
}

// Per t: clear Mb slot (real rows: t==0 odd-zero h_init, else even/invalid;
// pad rows odd-zero) and write per-group emb A-fragments.
__global__ __launch_bounds__(256) void init_kernel(
    const int* __restrict__ seq, const float* __restrict__ emb,
    unsigned short* __restrict__ Mb, unsigned short* __restrict__ Ae)
{
  const int t = blockIdx.x, tid = threadIdx.x;
  uint4* Mb4 = (uint4*)Mb + (size_t)t * (GRPS * MBU);
  const uint32_t zr = (t == 0) ? 0x00010001u : 0u;
  for (int u = tid; u < GRPS * MBU; u += 256) {
    const int rowp = u & 15;
    const uint32_t v = (rowp >= 8) ? 0x00010001u : zr;
    uint4 z; z.x = z.y = z.z = z.w = v;
    Mb4[u] = z;
  }
  for (int u = tid; u < GRPS * EBU; u += 256) {
    const int g = u >> 10, e = u & 1023;
    const int kcp = e >> 6, q = (e >> 4) & 3, rowp = e & 15;
    unsigned short pack[8];
    if (rowp < 8) {
      const int row = g * 8 + rowp;
      const int token = seq[row * Ssz + t];
      const float* src = emb + (size_t)token * Esz + kcp * 32 + q * 8;
      #pragma unroll
      for (int j = 0; j < 8; ++j) pack[j] = f2bf(src[j]);
    } else {
      #pragma unroll
      for (int j = 0; j < 8; ++j) pack[j] = 0;
    }
    *(uint4*)(Ae + (((size_t)g * Ssz + t) * EBU + e) * 8) = *(uint4*)pack;
  }
}

__global__ __launch_bounds__(256, 1) void lstm_kernel(
    const float* __restrict__ bias, const unsigned short* __restrict__ Wf,
    unsigned short* __restrict__ Mb, const unsigned short* __restrict__ Ae,
    float* __restrict__ out)
{
  extern __shared__ uint4 dynW[];               // 128 KB: 32 frags/wave
  __shared__ __align__(16) unsigned short Hs[4][8][8];

  const int tid  = threadIdx.x;
  const int lane = tid & 63, w = tid >> 6;
  const int l15  = lane & 15, quad = lane >> 4;
  const int g  = blockIdx.x & 7;                // XCD group (round-robin)
  const int GB = blockIdx.x >> 3;               // gcol-block within group
  const int base = GB * 32 + w * 8;             // wave's h-col base

  // ---- one-time: W-frags -> LDS (kc<16 both tiles) + VGPRs (kc 16..47)
  const uint4* wfb = (const uint4*)Wf + (size_t)(GB * 4 + w) * WFRAG * 64;
  for (int s = 0; s < 32; ++s) {
    const int tile = (s >= LDSF), kc = s - tile * LDSF;
    dynW[(w * 32 + s) * 64 + lane] = wfb[(tile * 48 + kc) * 64 + lane];
  }
  uint4 wr[64];
  #pragma unroll
  for (int s = 0; s < 64; ++s) {
    const int tile = (s >= 32), kc = 16 + (s - tile * 32);
    wr[s] = wfb[(tile * 48 + kc) * 64 + lane];
  }

  const bool owner = (l15 < 8) && (quad < 2);
  const int hc = l15 & 7;
  const float bi  = bias[base + hc],            bf_ = bias[Hsz + base + hc];
  const float bg_ = bias[2 * Hsz + base + hc],  bo  = bias[3 * Hsz + base + hc];
  float creg[4] = {0.f, 0.f, 0.f, 0.f};
  __syncthreads();

  uint4 eA[16];
  {
    const uint4* E0 = (const uint4*)Ae + (size_t)g * Ssz * EBU;
    #pragma unroll
    for (int i = 0; i < 16; ++i) eA[i] = E0[i * 64 + lane];
  }

  const u64 M = 0x0001000100010001ull;
  const int myu = GB * 64 + w * 16 + lane;      // producer unit idx (lane<8)
  int sc0_fail = 0;                             // adaptive kill-switch

  for (int t = 0; t < Ssz; ++t) {
    // ---- emb MFMAs (shadow; 2 chains per tile) ----
    f32x4 a0a = {0,0,0,0}, a0b = {0,0,0,0}, a1a = {0,0,0,0}, a1b = {0,0,0,0};
    #pragma unroll
    for (int i = 0; i < 16; ++i) {
      const bf16x8 a = __builtin_bit_cast(bf16x8, eA[i]);
      const bf16x8 b0 = __builtin_bit_cast(bf16x8, wr[16 + i]);
      const bf16x8 b1 = __builtin_bit_cast(bf16x8, wr[48 + i]);
      if (i & 1) { a0b = __builtin_amdgcn_mfma_f32_16x16x32_bf16(a, b0, a0b, 0,0,0);
                   a1b = __builtin_amdgcn_mfma_f32_16x16x32_bf16(a, b1, a1b, 0,0,0); }
      else       { a0a = __builtin_amdgcn_mfma_f32_16x16x32_bf16(a, b0, a0a, 0,0,0);
                   a1a = __builtin_amdgcn_mfma_f32_16x16x32_bf16(a, b1, a1a, 0,0,0); }
    }
    asm volatile("" ::: "memory");

    // ---- sc0 sweep of this step's virgin slot (L2-served, L1-bypass) ----
    const uint4* Mt = (const uint4*)Mb + (size_t)(t * GRPS + g) * MBU;
    uint4 ab[32];
    #pragma unroll
    for (int kc = 0; kc < 32; ++kc)
      asm volatile("global_load_dwordx4 %0, %1, off sc0"
                   : "=v"(ab[kc]) : "v"(Mt + kc * 64 + lane));
    asm volatile("s_waitcnt vmcnt(0)" ::: "memory");
    __builtin_amdgcn_sched_barrier(0);

    uint32_t bad = 0;
    #pragma unroll
    for (int kc = 0; kc < 32; ++kc) {
      u64 lo = ((u64)ab[kc].y << 32) | ab[kc].x;
      u64 hi = ((u64)ab[kc].w << 32) | ab[kc].z;
      if (((lo & M) != M) || ((hi & M) != M)) bad |= (1u << kc);
    }
    const int sc0_cap = (sc0_fail >= 4) ? 0 : 24;
    int rounds = 0;
    while (__any((int)(bad != 0u))) {
      ++rounds;
      __builtin_amdgcn_s_sleep(1);
      if (rounds <= sc0_cap) {
        #pragma unroll
        for (int kc = 0; kc < 32; ++kc)
          if (bad & (1u << kc))
            asm volatile("global_load_dwordx4 %0, %1, off sc0"
                         : "=v"(ab[kc]) : "v"(Mt + kc * 64 + lane));
        asm volatile("s_waitcnt vmcnt(0)" ::: "memory");
      } else {
        // agent path: MALL-direct; producers dual-store so this is fresh
        #pragma unroll
        for (int kc = 0; kc < 32; ++kc)
          if (bad & (1u << kc)) {
            const u64* bp = (const u64*)(Mt + kc * 64 + lane);
            u64 lo = __hip_atomic_load(bp,     __ATOMIC_RELAXED, __HIP_MEMORY_SCOPE_AGENT);
            u64 hi = __hip_atomic_load(bp + 1, __ATOMIC_RELAXED, __HIP_MEMORY_SCOPE_AGENT);
            ab[kc].x = (uint32_t)lo; ab[kc].y = (uint32_t)(lo >> 32);
            ab[kc].z = (uint32_t)hi; ab[kc].w = (uint32_t)(hi >> 32);
          }
      }
      __builtin_amdgcn_sched_barrier(0);
      uint32_t nb = 0;
      #pragma unroll
      for (int kc = 0; kc < 32; ++kc)
        if (bad & (1u << kc)) {
          u64 lo = ((u64)ab[kc].y << 32) | ab[kc].x;
          u64 hi = ((u64)ab[kc].w << 32) | ab[kc].z;
          if (((lo & M) != M) || ((hi & M) != M)) nb |= (1u << kc);
        }
      bad = nb;
    }
    if (rounds > sc0_cap) ++sc0_fail; else if (sc0_fail > 0 && rounds == 0) --sc0_fail;

    // ---- h MFMAs: B from LDS (kc<16) or VGPR (kc>=16) ----
    #pragma unroll
    for (int kc = 0; kc < 32; ++kc) {
      const bf16x8 a = __builtin_bit_cast(bf16x8, ab[kc]);
      bf16x8 b0, b1;
      if (kc < LDSF) {
        b0 = __builtin_bit_cast(bf16x8, dynW[(w * 32 + kc) * 64 + lane]);
        b1 = __builtin_bit_cast(bf16x8, dynW[(w * 32 + LDSF + kc) * 64 + lane]);
      } else {
        b0 = __builtin_bit_cast(bf16x8, wr[kc - 16]);
        b1 = __builtin_bit_cast(bf16x8, wr[32 + kc - 16]);
      }
      if (kc & 1) { a0b = __builtin_amdgcn_mfma_f32_16x16x32_bf16(a, b0, a0b, 0,0,0);
                    a1b = __builtin_amdgcn_mfma_f32_16x16x32_bf16(a, b1, a1b, 0,0,0); }
      else        { a0a = __builtin_amdgcn_mfma_f32_16x16x32_bf16(a, b0, a0a, 0,0,0);
                    a1a = __builtin_amdgcn_mfma_f32_16x16x32_bf16(a, b1, a1a, 0,0,0); }
    }
    f32x4 A0, A1;
    A0.x = a0a.x + a0b.x; A0.y = a0a.y + a0b.y; A0.z = a0a.z + a0b.z; A0.w = a0a.w + a0b.w;
    A1.x = a1a.x + a1b.x; A1.y = a1a.y + a1b.y; A1.z = a1a.z + a1b.z; A1.w = a1a.w + a1b.w;

    // ---- cell: tile0 cols = i(hc)/f(hc+8), tile1 = g/o; xor-8 shuffles ----
    float hv[4];
    #pragma unroll
    for (int r = 0; r < 4; ++r) {
      float iv = A0[r] + bi;
      float fv = __shfl_xor(A0[r], 8) + bf_;
      float gv = A1[r] + bg_;
      float ov = __shfl_xor(A1[r], 8) + bo;
      float c = fsig(fv) * creg[r] + fsig(iv) * ftanh(gv);
      float h = fsig(ov) * ftanh(c);
      if (owner) { creg[r] = c; hv[r] = h; }
    }

    if (t == Ssz - 1) {
      if (owner) {
        #pragma unroll
        for (int r = 0; r < 4; ++r) {
          const int row = g * 8 + quad * 4 + r;
          const int col = base + hc;
          out[(size_t)row * Hsz + col] = hv[r];
          out[(size_t)(Bsz * Hsz) + (size_t)row * Hsz + col] = creg[r];
        }
      }
      return;
    }

    // ---- produce h_t into slot t+1: in-wave transpose, dual store ----
    if (owner) {
      #pragma unroll
      for (int r = 0; r < 4; ++r) Hs[w][quad * 4 + r][hc] = f2bf_odd(hv[r]);
    }
    unsigned short* Mn = Mb + (size_t)((t + 1) * GRPS + g) * MBU * 8;
    if (lane < 8) {
      uint4 hp = *(const uint4*)&Hs[w][lane][0];
      *(uint4*)(Mn + (size_t)myu * 8) = hp;       // normal: own-L2 fast path
      u64 lo = ((u64)hp.y << 32) | hp.x;
      u64 hi = ((u64)hp.w << 32) | hp.z;
      u64* ap = (u64*)(Mn + (size_t)myu * 8);     // agent: same addr, same bytes
      __hip_atomic_store(ap,     lo, __ATOMIC_RELAXED, __HIP_MEMORY_SCOPE_AGENT);
      __hip_atomic_store(ap + 1, hi, __ATOMIC_RELAXED, __HIP_MEMORY_SCOPE_AGENT);
    }
    asm volatile("" ::: "memory");

    // ---- emb prefetch for t+1 (init-written, always valid) ----
    {
      const uint4* En = (const uint4*)Ae + ((size_t)g * Ssz + t + 1) * EBU;
      #pragma unroll
      for (int i = 0; i < 16; ++i) eA[i] = En[i * 64 + lane];
    }
  }
}

extern "C" void kernel_launch(void* const* d_in, const int* in_sizes, int n_in,
                              void* d_out, int out_size, void* d_ws, size_t ws_size,
                              hipStream_t stream) {
  (void)in_sizes; (void)n_in; (void)out_size; (void)ws_size;
  const int*   seq  = (const int*)d_in[0];     // [64][512] int32
  const float* emb  = (const float*)d_in[1];   // [32000][512] fp32
  const float* Wih  = (const float*)d_in[2];   // [512][4096] fp32
  const float* Whh  = (const float*)d_in[3];   // [1024][4096] fp32
  const float* bias = (const float*)d_in[4];   // [4096] fp32
  float* out = (float*)d_out;                  // h[64][1024] then c[64][1024]

  unsigned short* Wf = (unsigned short*)d_ws;                    // 12.58 MB
  unsigned short* Mb = Wf + (size_t)12288 * 64 * 8;              // 134.2 MB
  unsigned short* Ae = Mb + (size_t)Ssz * GRPS * MBU * 8;        // 67.1 MB

  (void)hipFuncSetAttribute((const void*)lstm_kernel,
                            hipFuncAttributeMaxDynamicSharedMemorySize, 131072);
  wf_kernel<<<3072, 256, 0, stream>>>(Wih, Whh, Wf);
  init_kernel<<<Ssz, 256, 0, stream>>>(seq, emb, Mb, Ae);
  lstm_kernel<<<NBLK, 256, 131072, stream>>>(bias, Wf, Mb, Ae, out);
}

// Round 10
// 2617.118 us; speedup vs baseline: 7.9050x; 7.9050x over previous
//
#include <hip/hip_runtime.h>
#include <stdint.h>

// LSTM encoder: B=64, S=512, V=32000, E=512, H=1024. Returns final (h, c) fp32.
//
// Round-19: r15 base (paced sweep + AIMD + batched recovery; 2506us) with
// geometry re-shape. r18 post-mortem: row-partitioning spilled 256+ VGPRs
// -> 15GB of scratch traffic; structurally dead (W/block 8x too big).
// r19 keeps the r15 sync protocol BYTE-IDENTICAL and cuts the two measured
// inefficiencies:
//  - Block = 8 h-cols x 32 rows (was 4 x 64): rb=blk&1, cb=blk>>1; waves =
//    2 row-tiles x 2 col-quads. Wave pairs (w0,w1)/(w2,w3) load identical
//    A-tiles (L1 dedup) -> sweep served-volume per XCD-L2 halves (4MB ->
//    2MB/step ~= -0.45us), unique MALL fetch halves.
//  - rb = blk&1 + round-robin dispatch => rb=0/rb=1 sub-systems fully
//    decoupled (128-producer straggler max, not 256; disjoint XCD parity).
//  - s_setprio(1) around h-MFMA+cell+store (producer critical path),
//    prio 0 during the pacing wait: cuts scheduling jitter.
//  - W slice 96KB -> dynamic LDS (proven in r18 under graph capture).
// Everything else (LSB-odd validity, per-run init clears, AIMD anchored
// pacing, batched agent recovery, emb shadow, 8B fire-and-forget stores)
// is r15-proven and unchanged.

#define Bsz 64
#define Ssz 512
#define Esz 512
#define Hsz 1024
#define G4  4096
#define Ksz 1536
#define KC  48      // Ksz/32
#define NBLK 256
#define AUNITS 12288            // 16B units per A buffer (KC*256)

#define D_INIT 400u
#define D_MIN  40u
#define D_MAX  1500u

typedef float f32x4 __attribute__((ext_vector_type(4)));
typedef short bf16x8 __attribute__((ext_vector_type(8)));
typedef unsigned long long u64;

// A unit(row,kc,q) = kc*256 + (row>>4)*64 + q*16 + (row&15)
// Wf unit(quad,kc,q8,r) = (quad*48+kc)*64 + q8*16 + r, r = gate*4+j (n-col)
//   (quad = global col-quad 0..255, owns h-cols quad*4..+4)

__device__ __forceinline__ unsigned short f2bf(float f) {
  union { float f; uint32_t u; } v; v.f = f;
  return (unsigned short)((v.u + 0x7FFFu + ((v.u >> 16) & 1u)) >> 16);  // RNE
}
// nearest ODD-LSB bf16 (validity bit). trunc|1 IS the nearest odd value.
__device__ __forceinline__ unsigned short f2bf_odd(float f) {
  union { float f; uint32_t u; } v; v.f = f;
  return (unsigned short)((v.u >> 16) | 1u);
}
__device__ __forceinline__ float fsig(float x) {
  return __builtin_amdgcn_rcpf(1.0f + __expf(-x));
}
__device__ __forceinline__ float ftanh(float x) {
  return 2.0f * fsig(2.0f * x) - 1.0f;
}

__global__ __launch_bounds__(1024) void wf_kernel(
    const float* __restrict__ Wih, const float* __restrict__ Whh,
    unsigned short* __restrict__ Wf)
{
  __shared__ float tile[32][33];
  const int j0 = blockIdx.x * 32;           // gate-col tile
  const int k0 = blockIdx.y * 32;           // k tile
  const int tx = threadIdx.x & 31, ty = threadIdx.x >> 5;
  const int k = k0 + ty;
  tile[ty][tx] = (k < Hsz) ? Whh[(size_t)k * G4 + (j0 + tx)]
                           : Wih[(size_t)(k - Hsz) * G4 + (j0 + tx)];
  __syncthreads();
  if (threadIdx.x < 128) {
    const int gl = threadIdx.x & 31;        // local gate col in tile
    const int q8 = threadIdx.x >> 5;        // k-octet within kc
    const int g  = j0 + gl;                 // global gate col
    const int quad = (g & 1023) >> 2;
    const int gate = g >> 10;
    const int r    = gate * 4 + (g & 3);    // n-col within quad tile
    const int kc   = k0 >> 5;
    unsigned short pack[8];
    #pragma unroll
    for (int jj = 0; jj < 8; ++jj) pack[jj] = f2bf(tile[q8 * 8 + jj][gl]);
    const size_t unit = (size_t)((quad * KC + kc) * 64 + q8 * 16 + r);
    *(bf16x8*)(Wf + unit * 8) = *(bf16x8*)pack;
  }
}

// Per A[t]: clear h region to even/invalid (t=0: odd-LSB "zero" h) and
// write the emb region. Clearing every run kills cross-run stale-valid data.
__global__ __launch_bounds__(256) void init_kernel(
    const int* __restrict__ seq, const float* __restrict__ emb,
    unsigned short* __restrict__ Abufs)
{
  const int t = blockIdx.x, tid = threadIdx.x;
  unsigned short* At = Abufs + (size_t)t * AUNITS * 8;
  {  // h region = units [0, 8192) = kc 0..31
    uint4 z;
    const uint32_t zv = (t == 0) ? 0x00010001u : 0u;
    z.x = z.y = z.z = z.w = zv;
    for (int i = tid; i < 8192; i += 256) ((uint4*)At)[i] = z;
  }
  const int c = 2 * tid;                    // emb col pair
  const int kc = 32 + (c >> 5), q = (c >> 3) & 3, j = c & 7;
  for (int row = 0; row < Bsz; ++row) {
    const int token = seq[row * Ssz + t];
    float2 e = ((const float2*)(emb + (size_t)token * Esz))[tid];
    uint32_t pe = (uint32_t)f2bf(e.x) | ((uint32_t)f2bf(e.y) << 16);
    const size_t unit = (size_t)(kc * 256 + (row >> 4) * 64 + q * 16 + (row & 15));
    *(uint32_t*)(At + unit * 8 + j) = pe;
  }
}

__global__ __launch_bounds__(256, 1) void lstm_kernel(
    const float* __restrict__ bias, const unsigned short* __restrict__ Wf,
    unsigned short* __restrict__ Abufs, float* __restrict__ out)
{
  extern __shared__ uint4 Wl[];                 // 96 KB: 2 col-quad slices
  __shared__ unsigned short Hs[4][16][4];       // 512 B per-wave h transpose

  const int tid  = threadIdx.x;
  const int lane = tid & 63;
  const int w    = tid >> 6;
  const int l15  = lane & 15, quad = lane >> 4;

  // block = (rb = blk&1 row-half, cb = blk>>1 col-octet). Round-robin
  // dispatch => XCD parity == rb: the two halves are decoupled systems.
  const int rb = blockIdx.x & 1;
  const int cb = blockIdx.x >> 1;
  const int rt = rb * 2 + (w >> 1);     // wave's global row-tile (16 rows)
  const int ct = cb * 2 + (w & 1);      // wave's global col-quad (4 cols)
  const int wh = (w & 1);               // which LDS W half this wave uses

  {  // one-time: 2 col-quad W slices -> dynamic LDS (96 KB)
    const uint4* wfb = (const uint4*)Wf + (size_t)(cb * 2) * (KC * 64);
    for (int i = tid; i < 2 * KC * 64; i += 256) Wl[i] = wfb[i];
  }

  // cell ownership: lanes l15<4 own (rows rt*16+quad*4+r, col ct*4+l15)
  const bool owner = (l15 < 4);
  const int  bj = ct * 4 + (l15 & 3);
  const float bi  = bias[bj],        bf_ = bias[Hsz + bj];
  const float bg_ = bias[2*Hsz + bj], bo  = bias[3*Hsz + bj];
  float creg[4] = {0.f, 0.f, 0.f, 0.f};

  // h-store addressing: wave's cols live at (hkc, hq, hj0)
  const int hkc = ct >> 3, hq = (ct >> 1) & 3, hj0 = (ct & 1) * 4;

  __syncthreads();                      // Wl staged (only block barrier)

  // ---- emb prefetch (1 step ahead) ----
  uint4 eA[16];
  {
    const uint4* E0 = (const uint4*)Abufs;
    #pragma unroll
    for (int i = 0; i < 16; ++i) eA[i] = E0[(32 + i) * 256 + rt * 64 + lane];
  }

  const u64 M = 0x0001000100010001ull;

  u64 dl = 0;                 // deadline for next sweep (anchored at V + D)
  uint32_t D = D_INIT;        // AIMD gap, native REFCLK ticks

  for (int t = 0; t < Ssz; ++t) {
    // ---- emb MFMAs (register-only), shadow work ----
    f32x4 accE = {0.f, 0.f, 0.f, 0.f};
    #pragma unroll
    for (int i = 0; i < 16; ++i)
      accE = __builtin_amdgcn_mfma_f32_16x16x32_bf16(
          __builtin_bit_cast(bf16x8, eA[i]),
          __builtin_bit_cast(bf16x8, Wl[(wh * KC + 32 + i) * 64 + lane]),
          accE, 0, 0, 0);

    // ---- pacing: wait for anchored deadline (terminates: clock monotone)
    while (__builtin_amdgcn_s_memrealtime() < dl) __builtin_amdgcn_s_sleep(1);
    asm volatile("" ::: "memory");

    // ---- single cached sweep kc=0..31 of wave's row-tile ----
    const uint4* Ac = (const uint4*)(Abufs + (size_t)t * AUNITS * 8);
    uint4 abuf[32];
    #pragma unroll
    for (int kc = 0; kc < 32; ++kc) abuf[kc] = Ac[kc * 256 + rt * 64 + lane];

    __builtin_amdgcn_sched_barrier(0);

    uint32_t bad = 0;
    #pragma unroll
    for (int kc = 0; kc < 32; ++kc) {
      u64 lo = ((u64)abuf[kc].y << 32) | abuf[kc].x;
      u64 hi = ((u64)abuf[kc].w << 32) | abuf[kc].z;
      if (((lo & M) != M) || ((hi & M) != M)) bad |= (1u << kc);
    }
    const bool missed = __any((int)(bad != 0u));

    // ---- batched recovery: concurrent agent reloads of bad units ----
    int rnd = 0;
    while (__any((int)(bad != 0u))) {
      if (rnd > 0) __builtin_amdgcn_s_sleep(2);
      ++rnd;
      #pragma unroll
      for (int kc = 0; kc < 32; ++kc) {
        if (bad & (1u << kc)) {
          const u64* base = (const u64*)Ac + (size_t)(kc * 256 + rt * 64 + lane) * 2;
          u64 lo = __hip_atomic_load(base,     __ATOMIC_RELAXED, __HIP_MEMORY_SCOPE_AGENT);
          u64 hi = __hip_atomic_load(base + 1, __ATOMIC_RELAXED, __HIP_MEMORY_SCOPE_AGENT);
          abuf[kc].x = (uint32_t)lo; abuf[kc].y = (uint32_t)(lo >> 32);
          abuf[kc].z = (uint32_t)hi; abuf[kc].w = (uint32_t)(hi >> 32);
        }
      }
      __builtin_amdgcn_sched_barrier(0);
      uint32_t nbad = 0;
      #pragma unroll
      for (int kc = 0; kc < 32; ++kc) {
        if (bad & (1u << kc)) {
          u64 lo = ((u64)abuf[kc].y << 32) | abuf[kc].x;
          u64 hi = ((u64)abuf[kc].w << 32) | abuf[kc].z;
          if (((lo & M) != M) || ((hi & M) != M)) nbad |= (1u << kc);
        }
      }
      bad = nbad;
    }

    // ---- anchor + AIMD: V (validation-complete) is a shared event ----
    {
      const u64 V = __builtin_amdgcn_s_memrealtime();
      if (missed) { D = (D + 12u > D_MAX) ? D_MAX : D + 12u; }
      else        { D = (D > D_MIN + 2u) ? D - 2u : D_MIN; }
      dl = V + (u64)D;
    }

    // ---- producer critical path: boost priority ----
    __builtin_amdgcn_s_setprio(1);

    // ---- h-GEMM: 32 MFMAs, 4 accumulation chains ----
    f32x4 acc0 = {0.f, 0.f, 0.f, 0.f};
    f32x4 acc1 = {0.f, 0.f, 0.f, 0.f};
    f32x4 acc2 = {0.f, 0.f, 0.f, 0.f};
    f32x4 acc3 = {0.f, 0.f, 0.f, 0.f};
    #pragma unroll
    for (int kc = 0; kc < 32; ++kc) {
      const bf16x8 av = __builtin_bit_cast(bf16x8, abuf[kc]);
      const bf16x8 bv = __builtin_bit_cast(bf16x8, Wl[(wh * KC + kc) * 64 + lane]);
      if      ((kc & 3) == 0) acc0 = __builtin_amdgcn_mfma_f32_16x16x32_bf16(av, bv, acc0, 0, 0, 0);
      else if ((kc & 3) == 1) acc1 = __builtin_amdgcn_mfma_f32_16x16x32_bf16(av, bv, acc1, 0, 0, 0);
      else if ((kc & 3) == 2) acc2 = __builtin_amdgcn_mfma_f32_16x16x32_bf16(av, bv, acc2, 0, 0, 0);
      else                    acc3 = __builtin_amdgcn_mfma_f32_16x16x32_bf16(av, bv, acc3, 0, 0, 0);
    }
    f32x4 acc;
    acc.x = accE.x + (acc0.x + acc1.x) + (acc2.x + acc3.x);
    acc.y = accE.y + (acc0.y + acc1.y) + (acc2.y + acc3.y);
    acc.z = accE.z + (acc0.z + acc1.z) + (acc2.z + acc3.z);
    acc.w = accE.w + (acc0.w + acc1.w) + (acc2.w + acc3.w);

    // ---- in-wave LSTM cell (acc[r]: gate l15>>2, col l15&3, row +quad*4+r)
    float hv[4];
    #pragma unroll
    for (int r = 0; r < 4; ++r) {
      float gf = __shfl_xor(acc[r], 4);
      float gg = __shfl_xor(acc[r], 8);
      float go = __shfl_xor(acc[r], 12);
      float c  = fsig(gf + bf_) * creg[r]
               + fsig(acc[r] + bi) * ftanh(gg + bg_);
      float h  = fsig(go + bo) * ftanh(c);
      if (owner) { creg[r] = c; hv[r] = h; }
    }

    if (t == Ssz - 1) {
      __builtin_amdgcn_s_setprio(0);
      if (owner) {
        #pragma unroll
        for (int r = 0; r < 4; ++r) {
          const int row = rt * 16 + quad * 4 + r;
          out[(size_t)row * Hsz + bj] = hv[r];
          out[(size_t)(Bsz * Hsz) + (size_t)row * Hsz + bj] = creg[r];
        }
      }
      return;
    }

    // ---- fire-and-forget: per-wave LDS transpose -> 8B odd-LSB u64 store
    if (owner) {
      #pragma unroll
      for (int r = 0; r < 4; ++r) Hs[w][quad * 4 + r][l15] = f2bf_odd(hv[r]);
    }
    unsigned short* An = Abufs + (size_t)(t + 1) * AUNITS * 8;
    if (lane < 16) {
      u64 hp = *(const u64*)&Hs[w][lane][0];
      const size_t unit = (size_t)(hkc * 256 + rt * 64 + hq * 16 + lane);
      __hip_atomic_store((u64*)(An + unit * 8 + hj0), hp,
                         __ATOMIC_RELAXED, __HIP_MEMORY_SCOPE_AGENT);
    }
    __builtin_amdgcn_s_setprio(0);
    asm volatile("" ::: "memory");

    // ---- refill emb prefetch for t+1 (init-written, always valid) ----
    const uint4* An4 = (const uint4*)An;
    #pragma unroll
    for (int i = 0; i < 16; ++i) eA[i] = An4[(32 + i) * 256 + rt * 64 + lane];
  }
}

extern "C" void kernel_launch(void* const* d_in, const int* in_sizes, int n_in,
                              void* d_out, int out_size, void* d_ws, size_t ws_size,
                              hipStream_t stream) {
  (void)in_sizes; (void)n_in; (void)out_size; (void)ws_size;
  const int*   seq  = (const int*)d_in[0];     // [64][512] int32
  const float* emb  = (const float*)d_in[1];   // [32000][512] fp32
  const float* Wih  = (const float*)d_in[2];   // [512][4096] fp32
  const float* Whh  = (const float*)d_in[3];   // [1024][4096] fp32
  const float* bias = (const float*)d_in[4];   // [4096] fp32
  float* out = (float*)d_out;                  // h[64][1024] then c[64][1024]

  unsigned short* Wf    = (unsigned short*)d_ws;              // 12.58 MB
  unsigned short* Abufs = Wf + (size_t)NBLK * KC * 64 * 8;    // 512*192KB

  (void)hipFuncSetAttribute((const void*)lstm_kernel,
                            hipFuncAttributeMaxDynamicSharedMemorySize,
                            2 * KC * 64 * 16);
  wf_kernel<<<dim3(G4 / 32, Ksz / 32), 1024, 0, stream>>>(Wih, Whh, Wf);
  init_kernel<<<Ssz, 256, 0, stream>>>(seq, emb, Abufs);
  lstm_kernel<<<NBLK, 256, 2 * KC * 64 * 16, stream>>>(bias, Wf, Abufs, out);
}